// Round 3
// baseline (8862.132 us; speedup 1.0000x reference)
//
#include <hip/hip_runtime.h>
#include <stdint.h>

// ---------- types / helpers ----------
typedef __bf16 bf16_t;
typedef bf16_t bf16x8 __attribute__((ext_vector_type(8)));
typedef float f32x4 __attribute__((ext_vector_type(4)));

__device__ __forceinline__ float bf2f(unsigned short u) {
  union { unsigned int i; float f; } x; x.i = ((unsigned int)u) << 16; return x.f;
}
__device__ __forceinline__ unsigned short f2bf(float f) {
  union { float f; unsigned int i; } x; x.f = f;
  unsigned int r = x.i + 0x7FFFu + ((x.i >> 16) & 1u);
  return (unsigned short)(r >> 16);
}

__global__ void fill_ident(float2* __restrict__ p) {
  int i = blockIdx.x * 256 + threadIdx.x;
  if (i < 768) p[i] = make_float2(1.f, 0.f);
}

struct f8 { float4 a, b; };

__device__ __forceinline__ f8 ld_c8(const float* __restrict__ X,
                                    const float* __restrict__ TE,
                                    const float* __restrict__ SE,
                                    size_t row, int cc) {
  const float* src = (cc < 256) ? X : ((cc < 512) ? TE : SE);
  const float* p = src + row * 256 + (cc & 255);
  f8 r; r.a = *(const float4*)p; r.b = *(const float4*)(p + 4);
  return r;
}

// split 8 fp32 into hi/lo bf16 planes
__device__ __forceinline__ void split_pack(const float4 a, const float4 b,
                                           uint4& hi, uint4& lo) {
  float f[8] = {a.x, a.y, a.z, a.w, b.x, b.y, b.z, b.w};
  unsigned sh[8], sl[8];
#pragma unroll
  for (int j = 0; j < 8; ++j) {
    unsigned short h = f2bf(f[j]);
    sh[j] = h;
    sl[j] = f2bf(f[j] - bf2f(h));
  }
  hi = make_uint4(sh[0] | (sh[1] << 16), sh[2] | (sh[3] << 16),
                  sh[4] | (sh[5] << 16), sh[6] | (sh[7] << 16));
  lo = make_uint4(sl[0] | (sl[1] << 16), sl[2] | (sl[3] << 16),
                  sl[4] | (sl[5] << 16), sl[6] | (sl[7] << 16));
}

// ---------- split-precision GEMM: C[M,Cout] = A[M,K] * W[Cout,K]^T + bias ----
// A fp32 (AMODE 0) or concat(X,TE,SE) fp32 (AMODE 1). W fp32.
// hi/lo bf16 split of both operands; 3 MFMAs -> ~fp32-accurate product.
// SMODE: 0 none, 1 raw bf16, 2 fused relu(BN) bf16, 3 fused relu(BN) fp32,
//        4 raw fp32.   PART: write per-block column sum/sumsq partials.
template<int AMODE, int SMODE, int PART>
__global__ __launch_bounds__(256) void gemm_sp(
    const float* __restrict__ A, const float* __restrict__ AX,
    const float* __restrict__ ATE, const float* __restrict__ ASE,
    const float* __restrict__ W, const float* __restrict__ bias,
    const float2* __restrict__ ssO,
    unsigned short* __restrict__ Cb, float* __restrict__ Cf,
    float* __restrict__ psum, float* __restrict__ psq,
    int K, int Cout, int pOff) {
  __shared__ unsigned short lAh[128 * 64];
  __shared__ unsigned short lAl[128 * 64];
  __shared__ unsigned short lBh[128 * 64];
  __shared__ unsigned short lBl[128 * 64];
  __shared__ float red[4][64][2];

  const int tid = threadIdx.x;
  const int lane = tid & 63, wid = tid >> 6;
  const int wr = wid >> 1, wc = wid & 1;
  const int l15 = lane & 15, l4 = lane >> 4;
  const int brow = blockIdx.x * 128, bcol = blockIdx.y * 128;

  f32x4 acc[4][4] = {};

  const int sr = tid >> 3;          // 0..31
  const int sc = (tid & 7) * 8;     // 0..56 (elements)
  const int sdst = sc ^ ((sr & 7) << 3);

  f8 va[4], vb[4];
#pragma unroll
  for (int ci = 0; ci < 4; ++ci) {
    size_t ar = (size_t)(brow + ci * 32 + sr);
    if constexpr (AMODE == 0) {
      const float* p = A + ar * K + sc;
      va[ci].a = *(const float4*)p; va[ci].b = *(const float4*)(p + 4);
    } else {
      va[ci] = ld_c8(AX, ATE, ASE, ar, sc);
    }
    const float* q = W + (size_t)(bcol + ci * 32 + sr) * K + sc;
    vb[ci].a = *(const float4*)q; vb[ci].b = *(const float4*)(q + 4);
  }

  const int axor = (l15 & 7) << 3;

  for (int kt = 0; kt < K; kt += 64) {
    __syncthreads();
#pragma unroll
    for (int ci = 0; ci < 4; ++ci) {
      int dst = ((ci * 32 + sr) << 6) + sdst;
      uint4 hi, lo;
      split_pack(va[ci].a, va[ci].b, hi, lo);
      *(uint4*)(lAh + dst) = hi; *(uint4*)(lAl + dst) = lo;
      split_pack(vb[ci].a, vb[ci].b, hi, lo);
      *(uint4*)(lBh + dst) = hi; *(uint4*)(lBl + dst) = lo;
    }
    if (kt + 64 < K) {
      int cc = kt + 64 + sc;
#pragma unroll
      for (int ci = 0; ci < 4; ++ci) {
        size_t ar = (size_t)(brow + ci * 32 + sr);
        if constexpr (AMODE == 0) {
          const float* p = A + ar * K + cc;
          va[ci].a = *(const float4*)p; va[ci].b = *(const float4*)(p + 4);
        } else {
          va[ci] = ld_c8(AX, ATE, ASE, ar, cc);
        }
        const float* q = W + (size_t)(bcol + ci * 32 + sr) * K + cc;
        vb[ci].a = *(const float4*)q; vb[ci].b = *(const float4*)(q + 4);
      }
    }
    __syncthreads();
#pragma unroll
    for (int ks = 0; ks < 2; ++ks) {
      const int cofs = (ks * 32 + l4 * 8) ^ axor;
      bf16x8 afh[4], afl[4], bfh[4], bfl[4];
#pragma unroll
      for (int m = 0; m < 4; ++m) {
        int off = ((wr * 64 + m * 16 + l15) << 6) + cofs;
        afh[m] = *(const bf16x8*)(lAh + off);
        afl[m] = *(const bf16x8*)(lAl + off);
      }
#pragma unroll
      for (int nn = 0; nn < 4; ++nn) {
        int off = ((wc * 64 + nn * 16 + l15) << 6) + cofs;
        bfh[nn] = *(const bf16x8*)(lBh + off);
        bfl[nn] = *(const bf16x8*)(lBl + off);
      }
#pragma unroll
      for (int m = 0; m < 4; ++m)
#pragma unroll
        for (int nn = 0; nn < 4; ++nn) {
          acc[m][nn] = __builtin_amdgcn_mfma_f32_16x16x32_bf16(afh[m], bfh[nn], acc[m][nn], 0, 0, 0);
          acc[m][nn] = __builtin_amdgcn_mfma_f32_16x16x32_bf16(afl[m], bfh[nn], acc[m][nn], 0, 0, 0);
          acc[m][nn] = __builtin_amdgcn_mfma_f32_16x16x32_bf16(afh[m], bfl[nn], acc[m][nn], 0, 0, 0);
        }
    }
  }

  float cs[4] = {0.f, 0.f, 0.f, 0.f}, cq[4] = {0.f, 0.f, 0.f, 0.f};
#pragma unroll
  for (int nn = 0; nn < 4; ++nn) {
    int col = bcol + wc * 64 + nn * 16 + l15;
    float bv = bias[col];
    float2 s2 = make_float2(1.f, 0.f);
    if constexpr (SMODE == 2 || SMODE == 3) s2 = ssO[col];
#pragma unroll
    for (int m = 0; m < 4; ++m) {
      int row0 = brow + wr * 64 + m * 16 + l4 * 4;
#pragma unroll
      for (int r = 0; r < 4; ++r) {
        float v = acc[m][nn][r] + bv;
        size_t idx = (size_t)(row0 + r) * Cout + col;
        if constexpr (SMODE == 1) Cb[idx] = f2bf(v);
        if constexpr (SMODE == 2) Cb[idx] = f2bf(fmaxf(v * s2.x + s2.y, 0.f));
        if constexpr (SMODE == 3) Cf[idx] = fmaxf(v * s2.x + s2.y, 0.f);
        if constexpr (SMODE == 4) Cf[idx] = v;
        if constexpr (PART) { cs[nn] += v; cq[nn] += v * v; }
      }
    }
  }
  if constexpr (PART) {
#pragma unroll
    for (int nn = 0; nn < 4; ++nn) {
      cs[nn] += __shfl_xor(cs[nn], 16); cs[nn] += __shfl_xor(cs[nn], 32);
      cq[nn] += __shfl_xor(cq[nn], 16); cq[nn] += __shfl_xor(cq[nn], 32);
    }
    __syncthreads();
    if (lane < 16) {
#pragma unroll
      for (int nn = 0; nn < 4; ++nn) {
        red[wid][nn * 16 + lane][0] = cs[nn];
        red[wid][nn * 16 + lane][1] = cq[nn];
      }
    }
    __syncthreads();
    if (tid < 128) {
      int w0 = tid >> 6, cl = tid & 63;
      float s = red[w0][cl][0] + red[w0 + 2][cl][0];
      float q = red[w0][cl][1] + red[w0 + 2][cl][1];
      psum[(size_t)(pOff + blockIdx.x) * Cout + bcol + tid] = s;
      psq[(size_t)(pOff + blockIdx.x) * Cout + bcol + tid] = q;
    }
  }
}

// ---------- BN stats finalize ----------
__global__ void bn_stats(const float* __restrict__ psum, const float* __restrict__ psq,
                         const float* __restrict__ g, const float* __restrict__ be,
                         float2* __restrict__ ss, int gridM, int Cout, float invR) {
  int c = blockIdx.x * blockDim.x + threadIdx.x;
  if (c >= Cout) return;
  float s = 0.f, q = 0.f;
  for (int i = 0; i < gridM; ++i) {
    s += psum[(size_t)i * Cout + c];
    q += psq[(size_t)i * Cout + c];
  }
  float mu = s * invR;
  float var = q * invR - mu * mu;
  float sc = g[c] * rsqrtf(var + 1e-5f);
  ss[c] = make_float2(sc, be[c] - mu * sc);
}

// ---------- attention, chunk-local (CB=1). q: bf16, k: bf16, v: fp32.
// BN+ReLU applied on load via ss (pass identity if already applied).
// Block = NQ*16 threads; grid = 500 (n). All pointers pre-offset to chunk.
template<int NK>
__global__ void attn_sm(const unsigned short* __restrict__ qy,
                        const unsigned short* __restrict__ ky,
                        const float* __restrict__ vy,
                        const float2* __restrict__ ssq, const float2* __restrict__ ssk,
                        const float2* __restrict__ ssv, float* __restrict__ out) {
  __shared__ float kl[NK][16][17];
  __shared__ float vl[NK][16][17];
  const int n = blockIdx.x;
  const int tid = threadIdx.x;
  for (int ch = tid; ch < NK * 32; ch += blockDim.x) {
    int t = ch >> 5, c8 = (ch & 31) * 8;
    size_t src = ((size_t)t * 500 + n) * 256 + c8;
    uint4 kv = *(const uint4*)(ky + src);
    float4 v0a = *(const float4*)(vy + src);
    float4 v0b = *(const float4*)(vy + src + 4);
    const unsigned short* kp = (const unsigned short*)&kv;
    float fv[8] = {v0a.x, v0a.y, v0a.z, v0a.w, v0b.x, v0b.y, v0b.z, v0b.w};
#pragma unroll
    for (int j = 0; j < 8; ++j) {
      int c = c8 + j;
      float2 sk = ssk[c], sv = ssv[c];
      kl[t][c >> 4][c & 15] = fmaxf(bf2f(kp[j]) * sk.x + sk.y, 0.f);
      vl[t][c >> 4][c & 15] = fmaxf(fv[j] * sv.x + sv.y, 0.f);
    }
  }
  __syncthreads();
  const int s = tid >> 4, h = tid & 15;
  unsigned short qraw[16];
  size_t qb = ((size_t)s * 500 + n) * 256 + h * 16;
  *(uint4*)qraw = *(const uint4*)(qy + qb);
  *(uint4*)(qraw + 8) = *(const uint4*)(qy + qb + 8);
  float qv[16];
#pragma unroll
  for (int c = 0; c < 16; ++c) {
    float2 sq = ssq[h * 16 + c];
    qv[c] = fmaxf(bf2f(qraw[c]) * sq.x + sq.y, 0.f);
  }
  float lg[NK], mx = -1e30f;
#pragma unroll
  for (int t = 0; t < NK; ++t) {
    float d = 0.f;
#pragma unroll
    for (int c = 0; c < 16; ++c) d += qv[c] * kl[t][h][c];
    lg[t] = d * 0.25f;
    mx = fmaxf(mx, lg[t]);
  }
  float sum = 0.f;
#pragma unroll
  for (int t = 0; t < NK; ++t) { lg[t] = __expf(lg[t] - mx); sum += lg[t]; }
  float inv = 1.f / sum;
  float o[16];
#pragma unroll
  for (int c = 0; c < 16; ++c) o[c] = 0.f;
#pragma unroll
  for (int t = 0; t < NK; ++t) {
    float p = lg[t] * inv;
#pragma unroll
    for (int c = 0; c < 16; ++c) o[c] += p * vl[t][h][c];
  }
  size_t ob = ((size_t)s * 500 + n) * 256 + h * 16;
  *(float4*)(out + ob)      = make_float4(o[0], o[1], o[2], o[3]);
  *(float4*)(out + ob + 4)  = make_float4(o[4], o[5], o[6], o[7]);
  *(float4*)(out + ob + 8)  = make_float4(o[8], o[9], o[10], o[11]);
  *(float4*)(out + ob + 12) = make_float4(o[12], o[13], o[14], o[15]);
}

// ---------- final: out = X + relu(BN(y)), y fp32 ----------
__global__ __launch_bounds__(256) void bn_relu_addx(
    const float* __restrict__ y, const float2* __restrict__ ss,
    const float* __restrict__ X, float* __restrict__ out) {
  int r = blockIdx.x * 8 + (threadIdx.x >> 5);
  int c8 = (threadIdx.x & 31) * 8;
  size_t idx = (size_t)r * 256 + c8;
  float4 y0 = *(const float4*)(y + idx);
  float4 y1 = *(const float4*)(y + idx + 4);
  float4 x0 = *(const float4*)(X + idx);
  float4 x1 = *(const float4*)(X + idx + 4);
  float yv[8] = {y0.x, y0.y, y0.z, y0.w, y1.x, y1.y, y1.z, y1.w};
  float ov[8];
#pragma unroll
  for (int j = 0; j < 8; ++j) {
    float2 sc = ss[c8 + j];
    ov[j] = fmaxf(yv[j] * sc.x + sc.y, 0.f);
  }
  *(float4*)(out + idx)     = make_float4(x0.x + ov[0], x0.y + ov[1], x0.z + ov[2], x0.w + ov[3]);
  *(float4*)(out + idx + 4) = make_float4(x1.x + ov[4], x1.y + ov[5], x1.z + ov[6], x1.w + ov[7]);
}

// ---------- launcher ----------
extern "C" void kernel_launch(void* const* d_in, const int* in_sizes, int n_in,
                              void* d_out, int out_size, void* d_ws, size_t ws_size,
                              hipStream_t stream) {
  (void)in_sizes; (void)n_in; (void)out_size; (void)ws_size;
  const float* X  = (const float*)d_in[0];
  const float* TE = (const float*)d_in[1];
  const float* SE = (const float*)d_in[2];
  const float* I  = (const float*)d_in[3];
  const float *Wf[8], *Bf[8], *Gf[8], *Zf[8];
  for (int l = 0; l < 8; ++l) {
    Wf[l] = (const float*)d_in[4 + l * 4 + 0];
    Bf[l] = (const float*)d_in[4 + l * 4 + 1];
    Gf[l] = (const float*)d_in[4 + l * 4 + 2];
    Zf[l] = (const float*)d_in[4 + l * 4 + 3];
  }

  char* w = (char*)d_ws;
  size_t off = 0;
  auto alloc = [&](size_t bytes) -> void* {
    void* p = w + off;
    off += (bytes + 255) & ~(size_t)255;
    return p;
  };

  // workspace (~316 MB total)
  float* psum0 = (float*)alloc((size_t)2000 * 768 * 4);
  float* psq0  = (float*)alloc((size_t)2000 * 768 * 4);
  float* psum1 = (float*)alloc((size_t)2000 * 256 * 4);
  float* psq1  = (float*)alloc((size_t)2000 * 256 * 4);
  float* psum2 = (float*)alloc((size_t)2000 * 256 * 4);
  float* psq2  = (float*)alloc((size_t)2000 * 256 * 4);
  float2* ss   = (float2*)alloc((size_t)9 * 768 * sizeof(float2));
  float2* ident = ss + 8 * 768;
  unsigned short* q0  = (unsigned short*)alloc((size_t)16000 * 256 * 2);
  unsigned short* k0  = (unsigned short*)alloc((size_t)96000 * 256 * 2);
  unsigned short* q1  = (unsigned short*)alloc((size_t)96000 * 256 * 2);
  float* v0           = (float*)alloc((size_t)96000 * 256 * 4);   // later y7
  float* o0c          = (float*)alloc((size_t)16000 * 256 * 4);
  float* Hc           = (float*)alloc((size_t)16000 * 768 * 4);
  unsigned short* k1c = (unsigned short*)alloc((size_t)16000 * 256 * 2);
  float* v1c          = (float*)alloc((size_t)16000 * 256 * 4);
  float* y7 = v0;
  float* o1 = (float*)d_out;       // fp32 scratch, overwritten by final kernel

  fill_ident<<<dim3(3), 256, 0, stream>>>(ident);

  // ---- stage 1: q0 (I, batch-broadcast), k0, v0, q1 ----
  gemm_sp<0, 1, 1><<<dim3(125, 2), 256, 0, stream>>>(
      I, nullptr, nullptr, nullptr, Wf[0], Bf[0], nullptr, q0, nullptr,
      psum0, psq0, 768, 256, 0);
  bn_stats<<<dim3(1), 256, 0, stream>>>(psum0, psq0, Gf[0], Zf[0], ss + 0 * 768, 125, 256, 1.f / 16000.f);
  gemm_sp<1, 1, 1><<<dim3(750, 2), 256, 0, stream>>>(
      nullptr, X, TE, SE, Wf[1], Bf[1], nullptr, k0, nullptr,
      psum0, psq0, 768, 256, 0);
  bn_stats<<<dim3(1), 256, 0, stream>>>(psum0, psq0, Gf[1], Zf[1], ss + 1 * 768, 750, 256, 1.f / 96000.f);
  gemm_sp<1, 4, 1><<<dim3(750, 2), 256, 0, stream>>>(
      nullptr, X, TE, SE, Wf[2], Bf[2], nullptr, nullptr, v0,
      psum0, psq0, 768, 256, 0);
  bn_stats<<<dim3(1), 256, 0, stream>>>(psum0, psq0, Gf[2], Zf[2], ss + 2 * 768, 750, 256, 1.f / 96000.f);
  gemm_sp<1, 1, 1><<<dim3(750, 2), 256, 0, stream>>>(
      nullptr, X, TE, SE, Wf[4], Bf[4], nullptr, q1, nullptr,
      psum0, psq0, 768, 256, 0);
  bn_stats<<<dim3(1), 256, 0, stream>>>(psum0, psq0, Gf[4], Zf[4], ss + 4 * 768, 750, 256, 1.f / 96000.f);

  const size_t cOff = (size_t)6000 * 256;   // per-batch rows in k0/v0/q1/o1

  // ---- P-a: attn0 + m0o partials -> H stats ----
  for (int cb = 0; cb < 16; ++cb) {
    attn_sm<12><<<dim3(500), 512, 0, stream>>>(
        q0, k0 + cb * cOff, v0 + cb * cOff,
        ss + 0 * 768, ss + 1 * 768, ss + 2 * 768, o0c);
    gemm_sp<0, 0, 1><<<dim3(125, 6), 256, 0, stream>>>(
        o0c, nullptr, nullptr, nullptr, Wf[3], Bf[3], nullptr, nullptr, nullptr,
        psum0, psq0, 256, 768, cb * 125);
  }
  bn_stats<<<dim3(3), 256, 0, stream>>>(psum0, psq0, Gf[3], Zf[3], ss + 3 * 768, 2000, 768, 1.f / 256000.f);

  // ---- P-b: H chunks (fused BN, fp32) -> m1k/m1v partials ----
  for (int cb = 0; cb < 16; ++cb) {
    attn_sm<12><<<dim3(500), 512, 0, stream>>>(
        q0, k0 + cb * cOff, v0 + cb * cOff,
        ss + 0 * 768, ss + 1 * 768, ss + 2 * 768, o0c);
    gemm_sp<0, 3, 0><<<dim3(125, 6), 256, 0, stream>>>(
        o0c, nullptr, nullptr, nullptr, Wf[3], Bf[3], ss + 3 * 768, nullptr, Hc,
        nullptr, nullptr, 256, 768, 0);
    gemm_sp<0, 0, 1><<<dim3(125, 2), 256, 0, stream>>>(
        Hc, nullptr, nullptr, nullptr, Wf[5], Bf[5], nullptr, nullptr, nullptr,
        psum1, psq1, 768, 256, cb * 125);
    gemm_sp<0, 0, 1><<<dim3(125, 2), 256, 0, stream>>>(
        Hc, nullptr, nullptr, nullptr, Wf[6], Bf[6], nullptr, nullptr, nullptr,
        psum2, psq2, 768, 256, cb * 125);
  }
  bn_stats<<<dim3(1), 256, 0, stream>>>(psum1, psq1, Gf[5], Zf[5], ss + 5 * 768, 2000, 256, 1.f / 256000.f);
  bn_stats<<<dim3(1), 256, 0, stream>>>(psum2, psq2, Gf[6], Zf[6], ss + 6 * 768, 2000, 256, 1.f / 256000.f);

  // ---- P-c: recompute H, fused k1/v1, attn1 -> o1 (in d_out) ----
  for (int cb = 0; cb < 16; ++cb) {
    attn_sm<12><<<dim3(500), 512, 0, stream>>>(
        q0, k0 + cb * cOff, v0 + cb * cOff,
        ss + 0 * 768, ss + 1 * 768, ss + 2 * 768, o0c);
    gemm_sp<0, 3, 0><<<dim3(125, 6), 256, 0, stream>>>(
        o0c, nullptr, nullptr, nullptr, Wf[3], Bf[3], ss + 3 * 768, nullptr, Hc,
        nullptr, nullptr, 256, 768, 0);
    gemm_sp<0, 2, 0><<<dim3(125, 2), 256, 0, stream>>>(
        Hc, nullptr, nullptr, nullptr, Wf[5], Bf[5], ss + 5 * 768, k1c, nullptr,
        nullptr, nullptr, 768, 256, 0);
    gemm_sp<0, 3, 0><<<dim3(125, 2), 256, 0, stream>>>(
        Hc, nullptr, nullptr, nullptr, Wf[6], Bf[6], ss + 6 * 768, nullptr, v1c,
        nullptr, nullptr, 768, 256, 0);
    attn_sm<32><<<dim3(500), 192, 0, stream>>>(
        q1 + cb * cOff, k1c, v1c,
        ss + 4 * 768, ident, ident, o1 + cb * cOff);
  }

  // ---- m1o + final ----
  gemm_sp<0, 4, 1><<<dim3(750, 2), 256, 0, stream>>>(
      o1, nullptr, nullptr, nullptr, Wf[7], Bf[7], nullptr, nullptr, y7,
      psum0, psq0, 256, 256, 0);
  bn_stats<<<dim3(1), 256, 0, stream>>>(psum0, psq0, Gf[7], Zf[7], ss + 7 * 768, 750, 256, 1.f / 96000.f);
  bn_relu_addx<<<dim3(12000), 256, 0, stream>>>(y7, ss + 7 * 768, X, (float*)d_out);
}

// Round 4
// 6051.435 us; speedup vs baseline: 1.4645x; 1.4645x over previous
//
#include <hip/hip_runtime.h>
#include <stdint.h>

// ---------- types / helpers ----------
typedef __bf16 bf16_t;
typedef bf16_t bf16x8 __attribute__((ext_vector_type(8)));
typedef float f32x4 __attribute__((ext_vector_type(4)));

__device__ __forceinline__ float bf2f(unsigned short u) {
  union { unsigned int i; float f; } x; x.i = ((unsigned int)u) << 16; return x.f;
}
__device__ __forceinline__ unsigned short f2bf(float f) {
  union { float f; unsigned int i; } x; x.f = f;
  unsigned int r = x.i + 0x7FFFu + ((x.i >> 16) & 1u);
  return (unsigned short)(r >> 16);
}

__global__ void fill_ident(float2* __restrict__ p) {
  int i = blockIdx.x * 256 + threadIdx.x;
  if (i < 768) p[i] = make_float2(1.f, 0.f);
}

struct f8 { float4 a, b; };

__device__ __forceinline__ f8 ld_c8(const float* __restrict__ X,
                                    const float* __restrict__ TE,
                                    const float* __restrict__ SE,
                                    size_t row, int cc) {
  const float* src = (cc < 256) ? X : ((cc < 512) ? TE : SE);
  const float* p = src + row * 256 + (cc & 255);
  f8 r; r.a = *(const float4*)p; r.b = *(const float4*)(p + 4);
  return r;
}

// split 8 fp32 into hi/lo bf16 planes
__device__ __forceinline__ void split_pack(const float4 a, const float4 b,
                                           uint4& hi, uint4& lo) {
  float f[8] = {a.x, a.y, a.z, a.w, b.x, b.y, b.z, b.w};
  unsigned sh[8], sl[8];
#pragma unroll
  for (int j = 0; j < 8; ++j) {
    unsigned short h = f2bf(f[j]);
    sh[j] = h;
    sl[j] = f2bf(f[j] - bf2f(h));
  }
  hi = make_uint4(sh[0] | (sh[1] << 16), sh[2] | (sh[3] << 16),
                  sh[4] | (sh[5] << 16), sh[6] | (sh[7] << 16));
  lo = make_uint4(sl[0] | (sl[1] << 16), sl[2] | (sl[3] << 16),
                  sl[4] | (sl[5] << 16), sl[6] | (sl[7] << 16));
}

// ---------- split-precision GEMM: C[M,Cout] = A[M,K] * W[Cout,K]^T + bias ----
// A fp32 (AMODE 0) or concat(X,TE,SE) fp32 (AMODE 1). W fp32.
// hi/lo bf16 split of both operands; 3 MFMAs -> ~fp32-accurate product.
// SMODE: 0 none, 1 raw bf16, 2 fused relu(BN) bf16, 3 fused relu(BN) fp32,
//        4 raw fp32.   PART: write per-block column sum/sumsq partials.
template<int AMODE, int SMODE, int PART>
__global__ __launch_bounds__(256) void gemm_sp(
    const float* __restrict__ A, const float* __restrict__ AX,
    const float* __restrict__ ATE, const float* __restrict__ ASE,
    const float* __restrict__ W, const float* __restrict__ bias,
    const float2* __restrict__ ssO,
    unsigned short* __restrict__ Cb, float* __restrict__ Cf,
    float* __restrict__ psum, float* __restrict__ psq,
    int K, int Cout, int pOff) {
  __shared__ unsigned short lAh[128 * 64];
  __shared__ unsigned short lAl[128 * 64];
  __shared__ unsigned short lBh[128 * 64];
  __shared__ unsigned short lBl[128 * 64];
  __shared__ float red[4][64][2];

  const int tid = threadIdx.x;
  const int lane = tid & 63, wid = tid >> 6;
  const int wr = wid >> 1, wc = wid & 1;
  const int l15 = lane & 15, l4 = lane >> 4;
  const int brow = blockIdx.x * 128, bcol = blockIdx.y * 128;

  f32x4 acc[4][4] = {};

  const int sr = tid >> 3;          // 0..31
  const int sc = (tid & 7) * 8;     // 0..56 (elements)
  const int sdst = sc ^ ((sr & 7) << 3);

  f8 va[4], vb[4];
#pragma unroll
  for (int ci = 0; ci < 4; ++ci) {
    size_t ar = (size_t)(brow + ci * 32 + sr);
    if constexpr (AMODE == 0) {
      const float* p = A + ar * K + sc;
      va[ci].a = *(const float4*)p; va[ci].b = *(const float4*)(p + 4);
    } else {
      va[ci] = ld_c8(AX, ATE, ASE, ar, sc);
    }
    const float* q = W + (size_t)(bcol + ci * 32 + sr) * K + sc;
    vb[ci].a = *(const float4*)q; vb[ci].b = *(const float4*)(q + 4);
  }

  const int axor = (l15 & 7) << 3;

  for (int kt = 0; kt < K; kt += 64) {
    __syncthreads();
#pragma unroll
    for (int ci = 0; ci < 4; ++ci) {
      int dst = ((ci * 32 + sr) << 6) + sdst;
      uint4 hi, lo;
      split_pack(va[ci].a, va[ci].b, hi, lo);
      *(uint4*)(lAh + dst) = hi; *(uint4*)(lAl + dst) = lo;
      split_pack(vb[ci].a, vb[ci].b, hi, lo);
      *(uint4*)(lBh + dst) = hi; *(uint4*)(lBl + dst) = lo;
    }
    if (kt + 64 < K) {
      int cc = kt + 64 + sc;
#pragma unroll
      for (int ci = 0; ci < 4; ++ci) {
        size_t ar = (size_t)(brow + ci * 32 + sr);
        if constexpr (AMODE == 0) {
          const float* p = A + ar * K + cc;
          va[ci].a = *(const float4*)p; va[ci].b = *(const float4*)(p + 4);
        } else {
          va[ci] = ld_c8(AX, ATE, ASE, ar, cc);
        }
        const float* q = W + (size_t)(bcol + ci * 32 + sr) * K + cc;
        vb[ci].a = *(const float4*)q; vb[ci].b = *(const float4*)(q + 4);
      }
    }
    __syncthreads();
#pragma unroll
    for (int ks = 0; ks < 2; ++ks) {
      const int cofs = (ks * 32 + l4 * 8) ^ axor;
      bf16x8 afh[4], afl[4], bfh[4], bfl[4];
#pragma unroll
      for (int m = 0; m < 4; ++m) {
        int off = ((wr * 64 + m * 16 + l15) << 6) + cofs;
        afh[m] = *(const bf16x8*)(lAh + off);
        afl[m] = *(const bf16x8*)(lAl + off);
      }
#pragma unroll
      for (int nn = 0; nn < 4; ++nn) {
        int off = ((wc * 64 + nn * 16 + l15) << 6) + cofs;
        bfh[nn] = *(const bf16x8*)(lBh + off);
        bfl[nn] = *(const bf16x8*)(lBl + off);
      }
#pragma unroll
      for (int m = 0; m < 4; ++m)
#pragma unroll
        for (int nn = 0; nn < 4; ++nn) {
          acc[m][nn] = __builtin_amdgcn_mfma_f32_16x16x32_bf16(afh[m], bfh[nn], acc[m][nn], 0, 0, 0);
          acc[m][nn] = __builtin_amdgcn_mfma_f32_16x16x32_bf16(afl[m], bfh[nn], acc[m][nn], 0, 0, 0);
          acc[m][nn] = __builtin_amdgcn_mfma_f32_16x16x32_bf16(afh[m], bfl[nn], acc[m][nn], 0, 0, 0);
        }
    }
  }

  float cs[4] = {0.f, 0.f, 0.f, 0.f}, cq[4] = {0.f, 0.f, 0.f, 0.f};
#pragma unroll
  for (int nn = 0; nn < 4; ++nn) {
    int col = bcol + wc * 64 + nn * 16 + l15;
    float bv = bias[col];
    float2 s2 = make_float2(1.f, 0.f);
    if constexpr (SMODE == 2 || SMODE == 3) s2 = ssO[col];
#pragma unroll
    for (int m = 0; m < 4; ++m) {
      int row0 = brow + wr * 64 + m * 16 + l4 * 4;
#pragma unroll
      for (int r = 0; r < 4; ++r) {
        float v = acc[m][nn][r] + bv;
        size_t idx = (size_t)(row0 + r) * Cout + col;
        if constexpr (SMODE == 1) Cb[idx] = f2bf(v);
        if constexpr (SMODE == 2) Cb[idx] = f2bf(fmaxf(v * s2.x + s2.y, 0.f));
        if constexpr (SMODE == 3) Cf[idx] = fmaxf(v * s2.x + s2.y, 0.f);
        if constexpr (SMODE == 4) Cf[idx] = v;
        if constexpr (PART) { cs[nn] += v; cq[nn] += v * v; }
      }
    }
  }
  if constexpr (PART) {
#pragma unroll
    for (int nn = 0; nn < 4; ++nn) {
      cs[nn] += __shfl_xor(cs[nn], 16); cs[nn] += __shfl_xor(cs[nn], 32);
      cq[nn] += __shfl_xor(cq[nn], 16); cq[nn] += __shfl_xor(cq[nn], 32);
    }
    __syncthreads();
    if (lane < 16) {
#pragma unroll
      for (int nn = 0; nn < 4; ++nn) {
        red[wid][nn * 16 + lane][0] = cs[nn];
        red[wid][nn * 16 + lane][1] = cq[nn];
      }
    }
    __syncthreads();
    if (tid < 128) {
      int w0 = tid >> 6, cl = tid & 63;
      float s = red[w0][cl][0] + red[w0 + 2][cl][0];
      float q = red[w0][cl][1] + red[w0 + 2][cl][1];
      psum[(size_t)(pOff + blockIdx.x) * Cout + bcol + tid] = s;
      psq[(size_t)(pOff + blockIdx.x) * Cout + bcol + tid] = q;
    }
  }
}

// ---------- BN stats finalize (parallel): grid = Cout/64, 1024 thr ----------
__global__ __launch_bounds__(1024) void bn_stats_par(
    const float* __restrict__ psum, const float* __restrict__ psq,
    const float* __restrict__ g, const float* __restrict__ be,
    float2* __restrict__ ss, int gridM, int Cout, float invR) {
  const int tid = threadIdx.x, lane = tid & 63, wv = tid >> 6;  // 16 waves
  const int c = blockIdx.x * 64 + lane;
  float s = 0.f, q = 0.f;
  for (int i = wv; i < gridM; i += 16) {
    s += psum[(size_t)i * Cout + c];
    q += psq[(size_t)i * Cout + c];
  }
  __shared__ float rs[16][64], rq[16][64];
  rs[wv][lane] = s; rq[wv][lane] = q;
  __syncthreads();
  if (tid < 64) {
    float S = 0.f, Q = 0.f;
#pragma unroll
    for (int w = 0; w < 16; ++w) { S += rs[w][tid]; Q += rq[w][tid]; }
    int cc = blockIdx.x * 64 + tid;
    float mu = S * invR;
    float var = Q * invR - mu * mu;
    float sc = g[cc] * rsqrtf(var + 1e-5f);
    ss[cc] = make_float2(sc, be[cc] - mu * sc);
  }
}

// ---------- attention. q bf16 (+BN ssq on load), k bf16 (+ssk), v bf16 or
// fp32 (+ssv). grid (500, nB); per-b strides (0 for chunked calls).
template<int NK, int NQ, int VBF>
__global__ void attn_sm(const unsigned short* __restrict__ qy,
                        const unsigned short* __restrict__ ky,
                        const void* __restrict__ vyv,
                        const float2* __restrict__ ssq, const float2* __restrict__ ssk,
                        const float2* __restrict__ ssv, float* __restrict__ out,
                        size_t qStride, size_t kvStride) {
  __shared__ float kl[NK][16][17];
  __shared__ float vl[NK][16][17];
  const int n = blockIdx.x, b = blockIdx.y;
  const int tid = threadIdx.x;
  const unsigned short* kyb = ky + (size_t)b * kvStride;
  for (int ch = tid; ch < NK * 32; ch += NQ * 16) {
    int t = ch >> 5, c8 = (ch & 31) * 8;
    size_t src = ((size_t)t * 500 + n) * 256 + c8;
    uint4 kv = *(const uint4*)(kyb + src);
    const unsigned short* kp = (const unsigned short*)&kv;
    float fv[8];
    if constexpr (VBF) {
      const unsigned short* vb = (const unsigned short*)vyv + (size_t)b * kvStride;
      uint4 vv = *(const uint4*)(vb + src);
      const unsigned short* vp = (const unsigned short*)&vv;
#pragma unroll
      for (int j = 0; j < 8; ++j) fv[j] = bf2f(vp[j]);
    } else {
      const float* vf = (const float*)vyv + (size_t)b * kvStride;
      float4 a = *(const float4*)(vf + src);
      float4 bb = *(const float4*)(vf + src + 4);
      fv[0]=a.x; fv[1]=a.y; fv[2]=a.z; fv[3]=a.w;
      fv[4]=bb.x; fv[5]=bb.y; fv[6]=bb.z; fv[7]=bb.w;
    }
#pragma unroll
    for (int j = 0; j < 8; ++j) {
      int c = c8 + j;
      float2 sk = ssk[c], sv = ssv[c];
      kl[t][c >> 4][c & 15] = fmaxf(bf2f(kp[j]) * sk.x + sk.y, 0.f);
      vl[t][c >> 4][c & 15] = fmaxf(fv[j] * sv.x + sv.y, 0.f);
    }
  }
  __syncthreads();
  const int s = tid >> 4, h = tid & 15;
  unsigned short qraw[16];
  size_t qb = (size_t)b * qStride + ((size_t)s * 500 + n) * 256 + h * 16;
  *(uint4*)qraw = *(const uint4*)(qy + qb);
  *(uint4*)(qraw + 8) = *(const uint4*)(qy + qb + 8);
  float qv[16];
#pragma unroll
  for (int c = 0; c < 16; ++c) {
    float2 sq = ssq[h * 16 + c];
    qv[c] = fmaxf(bf2f(qraw[c]) * sq.x + sq.y, 0.f);
  }
  float lg[NK], mx = -1e30f;
#pragma unroll
  for (int t = 0; t < NK; ++t) {
    float d = 0.f;
#pragma unroll
    for (int c = 0; c < 16; ++c) d += qv[c] * kl[t][h][c];
    lg[t] = d * 0.25f;
    mx = fmaxf(mx, lg[t]);
  }
  float sum = 0.f;
#pragma unroll
  for (int t = 0; t < NK; ++t) { lg[t] = __expf(lg[t] - mx); sum += lg[t]; }
  float inv = 1.f / sum;
  float o[16];
#pragma unroll
  for (int c = 0; c < 16; ++c) o[c] = 0.f;
#pragma unroll
  for (int t = 0; t < NK; ++t) {
    float p = lg[t] * inv;
#pragma unroll
    for (int c = 0; c < 16; ++c) o[c] += p * vl[t][h][c];
  }
  size_t ob = (size_t)b * qStride + ((size_t)s * 500 + n) * 256 + h * 16;
  *(float4*)(out + ob)      = make_float4(o[0], o[1], o[2], o[3]);
  *(float4*)(out + ob + 4)  = make_float4(o[4], o[5], o[6], o[7]);
  *(float4*)(out + ob + 8)  = make_float4(o[8], o[9], o[10], o[11]);
  *(float4*)(out + ob + 12) = make_float4(o[12], o[13], o[14], o[15]);
}

// ---------- final: out = X + relu(BN(y)), y fp32 ----------
__global__ __launch_bounds__(256) void bn_relu_addx(
    const float* __restrict__ y, const float2* __restrict__ ss,
    const float* __restrict__ X, float* __restrict__ out) {
  int r = blockIdx.x * 8 + (threadIdx.x >> 5);
  int c8 = (threadIdx.x & 31) * 8;
  size_t idx = (size_t)r * 256 + c8;
  float4 y0 = *(const float4*)(y + idx);
  float4 y1 = *(const float4*)(y + idx + 4);
  float4 x0 = *(const float4*)(X + idx);
  float4 x1 = *(const float4*)(X + idx + 4);
  float yv[8] = {y0.x, y0.y, y0.z, y0.w, y1.x, y1.y, y1.z, y1.w};
  float ov[8];
#pragma unroll
  for (int j = 0; j < 8; ++j) {
    float2 sc = ss[c8 + j];
    ov[j] = fmaxf(yv[j] * sc.x + sc.y, 0.f);
  }
  *(float4*)(out + idx)     = make_float4(x0.x + ov[0], x0.y + ov[1], x0.z + ov[2], x0.w + ov[3]);
  *(float4*)(out + idx + 4) = make_float4(x1.x + ov[4], x1.y + ov[5], x1.z + ov[6], x1.w + ov[7]);
}

// ---------- launcher ----------
extern "C" void kernel_launch(void* const* d_in, const int* in_sizes, int n_in,
                              void* d_out, int out_size, void* d_ws, size_t ws_size,
                              hipStream_t stream) {
  (void)in_sizes; (void)n_in; (void)out_size;
  const float* X  = (const float*)d_in[0];
  const float* TE = (const float*)d_in[1];
  const float* SE = (const float*)d_in[2];
  const float* I  = (const float*)d_in[3];
  const float *Wf[8], *Bf[8], *Gf[8], *Zf[8];
  for (int l = 0; l < 8; ++l) {
    Wf[l] = (const float*)d_in[4 + l * 4 + 0];
    Bf[l] = (const float*)d_in[4 + l * 4 + 1];
    Gf[l] = (const float*)d_in[4 + l * 4 + 2];
    Zf[l] = (const float*)d_in[4 + l * 4 + 3];
  }

  const bool midWS = ws_size >= 560000000ULL;   // full-k1/v1 tier ≈ 552 MB

  char* w = (char*)d_ws;
  size_t off = 0;
  auto alloc = [&](size_t bytes) -> void* {
    void* p = w + off;
    off += (bytes + 255) & ~(size_t)255;
    return p;
  };

  float* psum0 = (float*)alloc((size_t)2000 * 768 * 4);
  float* psq0  = (float*)alloc((size_t)2000 * 768 * 4);
  float* psum1 = (float*)alloc((size_t)2000 * 256 * 4);
  float* psq1  = (float*)alloc((size_t)2000 * 256 * 4);
  float* psum2 = (float*)alloc((size_t)2000 * 256 * 4);
  float* psq2  = (float*)alloc((size_t)2000 * 256 * 4);
  float2* ss   = (float2*)alloc((size_t)9 * 768 * sizeof(float2));
  float2* ident = ss + 8 * 768;
  unsigned short* q0  = (unsigned short*)alloc((size_t)16000 * 256 * 2);
  unsigned short* k0  = (unsigned short*)alloc((size_t)96000 * 256 * 2);
  unsigned short* q1  = (unsigned short*)alloc((size_t)96000 * 256 * 2);
  float* v0           = (float*)alloc((size_t)96000 * 256 * 4);   // later y7
  float* o0c          = (float*)alloc((size_t)16000 * 256 * 4);
  float* Hc           = (float*)alloc((size_t)16000 * 768 * 4);
  unsigned short* k1b = nullptr; float* v1c = nullptr; unsigned short* v1b = nullptr;
  if (midWS) {
    k1b = (unsigned short*)alloc((size_t)256000 * 256 * 2);  // raw k1, bf16
    v1b = (unsigned short*)alloc((size_t)256000 * 256 * 2);  // raw v1, bf16
  } else {
    k1b = (unsigned short*)alloc((size_t)16000 * 256 * 2);   // per-chunk, BN'd
    v1c = (float*)alloc((size_t)16000 * 256 * 4);
  }
  float* y7 = v0;
  float* o1 = (float*)d_out;

  fill_ident<<<dim3(3), 256, 0, stream>>>(ident);

  // ---- stage 1: q0 (I, batch-broadcast), k0, v0, q1 ----
  gemm_sp<0, 1, 1><<<dim3(125, 2), 256, 0, stream>>>(
      I, nullptr, nullptr, nullptr, Wf[0], Bf[0], nullptr, q0, nullptr,
      psum0, psq0, 768, 256, 0);
  bn_stats_par<<<dim3(4), 1024, 0, stream>>>(psum0, psq0, Gf[0], Zf[0], ss + 0 * 768, 125, 256, 1.f / 16000.f);
  gemm_sp<1, 1, 1><<<dim3(750, 2), 256, 0, stream>>>(
      nullptr, X, TE, SE, Wf[1], Bf[1], nullptr, k0, nullptr,
      psum0, psq0, 768, 256, 0);
  bn_stats_par<<<dim3(4), 1024, 0, stream>>>(psum0, psq0, Gf[1], Zf[1], ss + 1 * 768, 750, 256, 1.f / 96000.f);
  gemm_sp<1, 4, 1><<<dim3(750, 2), 256, 0, stream>>>(
      nullptr, X, TE, SE, Wf[2], Bf[2], nullptr, nullptr, v0,
      psum0, psq0, 768, 256, 0);
  bn_stats_par<<<dim3(4), 1024, 0, stream>>>(psum0, psq0, Gf[2], Zf[2], ss + 2 * 768, 750, 256, 1.f / 96000.f);
  gemm_sp<1, 1, 1><<<dim3(750, 2), 256, 0, stream>>>(
      nullptr, X, TE, SE, Wf[4], Bf[4], nullptr, q1, nullptr,
      psum0, psq0, 768, 256, 0);
  bn_stats_par<<<dim3(4), 1024, 0, stream>>>(psum0, psq0, Gf[4], Zf[4], ss + 4 * 768, 750, 256, 1.f / 96000.f);

  const size_t cOff = (size_t)6000 * 256;    // per-batch rows in k0/v0/q1/o1
  const size_t cOff1 = (size_t)16000 * 256;  // per-batch rows in o0/H/k1/v1

  // ---- P-a: attn0 + m0o partials -> H stats ----
  for (int cb = 0; cb < 16; ++cb) {
    attn_sm<12, 32, 0><<<dim3(500, 1), 512, 0, stream>>>(
        q0, k0 + cb * cOff, v0 + cb * cOff,
        ss + 0 * 768, ss + 1 * 768, ss + 2 * 768, o0c, 0, 0);
    gemm_sp<0, 0, 1><<<dim3(125, 6), 256, 0, stream>>>(
        o0c, nullptr, nullptr, nullptr, Wf[3], Bf[3], nullptr, nullptr, nullptr,
        psum0, psq0, 256, 768, cb * 125);
  }
  bn_stats_par<<<dim3(12), 1024, 0, stream>>>(psum0, psq0, Gf[3], Zf[3], ss + 3 * 768, 2000, 768, 1.f / 256000.f);

  // ---- P-b: H chunks (fused BN, fp32) -> m1k/m1v ----
  for (int cb = 0; cb < 16; ++cb) {
    attn_sm<12, 32, 0><<<dim3(500, 1), 512, 0, stream>>>(
        q0, k0 + cb * cOff, v0 + cb * cOff,
        ss + 0 * 768, ss + 1 * 768, ss + 2 * 768, o0c, 0, 0);
    gemm_sp<0, 3, 0><<<dim3(125, 6), 256, 0, stream>>>(
        o0c, nullptr, nullptr, nullptr, Wf[3], Bf[3], ss + 3 * 768, nullptr, Hc,
        nullptr, nullptr, 256, 768, 0);
    if (midWS) {
      gemm_sp<0, 1, 1><<<dim3(125, 2), 256, 0, stream>>>(
          Hc, nullptr, nullptr, nullptr, Wf[5], Bf[5], nullptr,
          k1b + cb * cOff1, nullptr, psum1, psq1, 768, 256, cb * 125);
      gemm_sp<0, 1, 1><<<dim3(125, 2), 256, 0, stream>>>(
          Hc, nullptr, nullptr, nullptr, Wf[6], Bf[6], nullptr,
          v1b + cb * cOff1, nullptr, psum2, psq2, 768, 256, cb * 125);
    } else {
      gemm_sp<0, 0, 1><<<dim3(125, 2), 256, 0, stream>>>(
          Hc, nullptr, nullptr, nullptr, Wf[5], Bf[5], nullptr, nullptr, nullptr,
          psum1, psq1, 768, 256, cb * 125);
      gemm_sp<0, 0, 1><<<dim3(125, 2), 256, 0, stream>>>(
          Hc, nullptr, nullptr, nullptr, Wf[6], Bf[6], nullptr, nullptr, nullptr,
          psum2, psq2, 768, 256, cb * 125);
    }
  }
  bn_stats_par<<<dim3(4), 1024, 0, stream>>>(psum1, psq1, Gf[5], Zf[5], ss + 5 * 768, 2000, 256, 1.f / 256000.f);
  bn_stats_par<<<dim3(4), 1024, 0, stream>>>(psum2, psq2, Gf[6], Zf[6], ss + 6 * 768, 2000, 256, 1.f / 256000.f);

  // ---- attn1 ----
  if (midWS) {
    attn_sm<32, 12, 1><<<dim3(500, 16), 192, 0, stream>>>(
        q1, k1b, v1b, ss + 4 * 768, ss + 5 * 768, ss + 6 * 768, o1, cOff, cOff1);
  } else {
    // P-c: recompute H per chunk, fused k1/v1, attn1 per chunk
    for (int cb = 0; cb < 16; ++cb) {
      attn_sm<12, 32, 0><<<dim3(500, 1), 512, 0, stream>>>(
          q0, k0 + cb * cOff, v0 + cb * cOff,
          ss + 0 * 768, ss + 1 * 768, ss + 2 * 768, o0c, 0, 0);
      gemm_sp<0, 3, 0><<<dim3(125, 6), 256, 0, stream>>>(
          o0c, nullptr, nullptr, nullptr, Wf[3], Bf[3], ss + 3 * 768, nullptr, Hc,
          nullptr, nullptr, 256, 768, 0);
      gemm_sp<0, 2, 0><<<dim3(125, 2), 256, 0, stream>>>(
          Hc, nullptr, nullptr, nullptr, Wf[5], Bf[5], ss + 5 * 768, k1b, nullptr,
          nullptr, nullptr, 768, 256, 0);
      gemm_sp<0, 3, 0><<<dim3(125, 2), 256, 0, stream>>>(
          Hc, nullptr, nullptr, nullptr, Wf[6], Bf[6], ss + 6 * 768, nullptr, v1c,
          nullptr, nullptr, 768, 256, 0);
      attn_sm<32, 12, 0><<<dim3(500, 1), 192, 0, stream>>>(
          q1 + cb * cOff, k1b, v1c,
          ss + 4 * 768, ident, ident, o1 + cb * cOff, 0, 0);
    }
  }

  // ---- m1o + final ----
  gemm_sp<0, 4, 1><<<dim3(750, 2), 256, 0, stream>>>(
      o1, nullptr, nullptr, nullptr, Wf[7], Bf[7], nullptr, nullptr, y7,
      psum0, psq0, 256, 256, 0);
  bn_stats_par<<<dim3(4), 1024, 0, stream>>>(psum0, psq0, Gf[7], Zf[7], ss + 7 * 768, 750, 256, 1.f / 96000.f);
  bn_relu_addx<<<dim3(12000), 256, 0, stream>>>(y7, ss + 7 * 768, X, (float*)d_out);
}